// Round 10
// baseline (524.860 us; speedup 1.0000x reference)
//
#include <hip/hip_runtime.h>
#include <math.h>

#define BATCH 2
#define NPTS 4096
#define CH_C 128
#define MTOT 8192
#define KNN 16
#define NKP 43
#define PCSZ (NKP*CH_C)   // 5504
#define NCH 128           // wkv chunks
#define CHL (NPTS/NCH)    // 32 steps per chunk
#define CAP 128           // survivor list cap per query

typedef unsigned short ushort_t;
typedef __attribute__((ext_vector_type(8))) short bf16x8;
typedef __attribute__((ext_vector_type(4))) float f32x4;

// ---------------- ws layout (float offsets) ----------------
static const size_t OFF_XYZ  = 0;                       // 24576 floats
static const size_t OFF_SQ   = 24576;                   // 8192
static const size_t OFF_KPTS = 32768;                   // 129 -> pad 256
static const size_t OFF_BNST = 33024;                   // 256 (mu,rstd)
static const size_t OFF_BNP  = 33280;                   // doubles: 16384 d
static const size_t OFF_IDX  = 66048;                   // ints: 131072
static const size_t OFF_BUF  = 197120;                  // 9 x 1048576 float buffers
static const size_t OFF_G    = OFF_BUF + 9ull*1048576ull; // 9634304
// G region time-shared: knn sd/si/cnt -> KPConv G(bf16) -> wkv sum/carry -> HIDu(bf16)
static const size_t OFF_WT1  = OFF_G + 22544384ull;     // bf16 5504*128 = 352256 float slots
static const size_t OFF_WT2  = OFF_WT1 + 352256ull;
static const size_t OFF_WTA  = OFF_WT2 + 352256ull;     // 5 x 128x128 bf16 = 40960 slots
static const size_t OFF_WTFK = OFF_WTA + 40960ull;      // 512x128 bf16 = 32768 slots
static const size_t OFF_WTFV = OFF_WTFK + 32768ull;     // 128x512 bf16 = 32768 slots
static const size_t WS_TOP   = OFF_WTFV + 32768ull;

__device__ inline ushort_t f2bf(float f) {
  unsigned int u = __builtin_bit_cast(unsigned int, f);
  u = u + 0x7fffu + ((u >> 16) & 1u);
  return (ushort_t)(u >> 16);
}

// ---------------- kernels ----------------

__global__ void k_kpts(float* kpts) {
  int i = threadIdx.x;
  if (i >= NKP) return;
  double px = 0.0, py = 0.0, pz = 0.0;
  if (i > 0) {
    int mcount = (i < 15) ? 14 : 28;
    int ii = (i < 15) ? (i - 1) : (i - 15);
    double scale = (i < 15) ? (0.1 * 0.5) : 0.1;
    double id = (double)ii + 0.5;
    double phi = acos(1.0 - 2.0 * id / (double)mcount);
    double theta = M_PI * (1.0 + sqrt(5.0)) * id;
    px = cos(theta) * sin(phi) * scale;
    py = sin(theta) * sin(phi) * scale;
    pz = cos(phi) * scale;
  }
  kpts[3*i] = (float)px; kpts[3*i+1] = (float)py; kpts[3*i+2] = (float)pz;
}

__global__ __launch_bounds__(256) void k_zero(int* __restrict__ cnt) {
  cnt[blockIdx.x * 256 + threadIdx.x] = 0;
}

__global__ __launch_bounds__(256) void k_zerof(float* __restrict__ buf) {
  buf[(size_t)blockIdx.x * 256 + threadIdx.x] = 0.f;
}

__global__ __launch_bounds__(256) void k_prep(const float* __restrict__ p, float* __restrict__ xyz, float* __restrict__ sq) {
  int m = blockIdx.x * 256 + threadIdx.x;
  int b = m >> 12, n = m & 4095;
  float px = p[(size_t)b*12288 + n];
  float py = p[(size_t)b*12288 + 4096 + n];
  float pz = p[(size_t)b*12288 + 8192 + n];
  xyz[3*m] = px; xyz[3*m+1] = py; xyz[3*m+2] = pz;
  sq[m] = (px*px + py*py) + pz*pz;
}

// x [B,C,N] -> F0 [M][C]
__global__ __launch_bounds__(256) void k_tx(const float* __restrict__ x, float* __restrict__ F0) {
  __shared__ float t[32][33];
  int b = blockIdx.z;
  int n0 = blockIdx.x * 32, c0 = blockIdx.y * 32;
  int tx = threadIdx.x, ty = threadIdx.y;
  #pragma unroll
  for (int i = 0; i < 4; i++)
    t[ty + i*8][tx] = x[(size_t)b*524288 + (size_t)(c0 + ty + i*8)*4096 + n0 + tx];
  __syncthreads();
  #pragma unroll
  for (int i = 0; i < 4; i++)
    F0[(size_t)(b*4096 + n0 + ty + i*8)*128 + c0 + tx] = t[tx][ty + i*8];
}

// P3 [M][C] -> y [B,C,N]
__global__ __launch_bounds__(256) void k_ty(const float* __restrict__ P3, float* __restrict__ y) {
  __shared__ float t[32][33];
  int b = blockIdx.z;
  int n0 = blockIdx.x * 32, c0 = blockIdx.y * 32;
  int tx = threadIdx.x, ty = threadIdx.y;
  #pragma unroll
  for (int i = 0; i < 4; i++)
    t[ty + i*8][tx] = P3[(size_t)(b*4096 + n0 + ty + i*8)*128 + c0 + tx];
  __syncthreads();
  #pragma unroll
  for (int i = 0; i < 4; i++)
    y[(size_t)b*524288 + (size_t)(c0 + ty + i*8)*4096 + n0 + tx] = t[tx][ty + i*8];
}

// W [K][N] fp32 -> WT [N][K] bf16, grid (K/32, N/32)
__global__ __launch_bounds__(256) void k_wt(const float* __restrict__ Wm, ushort_t* __restrict__ WT, int K, int N) {
  __shared__ float t[32][33];
  int k0 = blockIdx.x * 32, n0 = blockIdx.y * 32;
  int tx = threadIdx.x & 31, ty = threadIdx.x >> 5;
  #pragma unroll
  for (int i = 0; i < 4; i++)
    t[ty + i*8][tx] = Wm[(size_t)(k0 + ty + i*8)*N + n0 + tx];
  __syncthreads();
  #pragma unroll
  for (int i = 0; i < 4; i++)
    WT[(size_t)(n0 + ty + i*8)*K + k0 + tx] = f2bf(t[tx][ty + i*8]);
}

// five 128x128 weights -> WT slots, grid (4,4,5)
__global__ __launch_bounds__(256) void k_wt5(const float* w0, const float* w1, const float* w2,
                                             const float* w3, const float* w4, ushort_t* WT) {
  const float* Wm = (blockIdx.z==0)?w0:(blockIdx.z==1)?w1:(blockIdx.z==2)?w2:(blockIdx.z==3)?w3:w4;
  ushort_t* dst = WT + (size_t)blockIdx.z * 16384;
  __shared__ float t[32][33];
  int k0 = blockIdx.x * 32, n0 = blockIdx.y * 32;
  int tx = threadIdx.x & 31, ty = threadIdx.x >> 5;
  #pragma unroll
  for (int i = 0; i < 4; i++)
    t[ty + i*8][tx] = Wm[(size_t)(k0 + ty + i*8)*128 + n0 + tx];
  __syncthreads();
  #pragma unroll
  for (int i = 0; i < 4; i++)
    dst[(size_t)(n0 + ty + i*8)*128 + k0 + tx] = f2bf(t[tx][ty + i*8]);
}

// phase A: radius compaction. 32 queries/block x 32 segments of 128 cands.
__global__ __launch_bounds__(1024) void k_knna(const float* __restrict__ xyz, const float* __restrict__ sq,
                                               float* __restrict__ sd, int* __restrict__ si,
                                               int* __restrict__ cnt) {
  __shared__ float4 s_c[NPTS];
  int tid = threadIdx.x;
  int m0 = blockIdx.x * 32;
  int b = m0 >> 12;
  int jbase = b << 12;
  for (int j = tid; j < NPTS; j += 1024) {
    int jj = jbase + j;
    s_c[j] = make_float4(xyz[3*jj], xyz[3*jj+1], xyz[3*jj+2], sq[jj]);
  }
  __syncthreads();
  int q = tid & 31, s = tid >> 5;
  int m = m0 + q;
  int lq = m - jbase;
  float4 me = s_c[lq];
  float ox = me.x, oy = me.y, oz = me.z, osq = me.w;
  const float RAD2 = (float)(0.1 * 0.1);
  int cbase = s * 128;
  for (int jj = 0; jj < 128; jj++) {
    float4 cp = s_c[cbase + jj];
    float dot = (ox*cp.x + oy*cp.y) + oz*cp.z;
    float d2 = (osq + cp.w) - 2.0f*dot;
    if (d2 <= RAD2) {
      int pos = atomicAdd(&cnt[m], 1);
      if (pos < CAP) {
        sd[(size_t)m*CAP + pos] = d2;
        si[(size_t)m*CAP + pos] = jbase + cbase + jj;
      }
    }
  }
}

// phase B: deterministic top-16 via (d2, idx)-lexicographic insert chain
#define INS2(T,TM) { bool sh = (bd##TM > d2) || (bd##TM == d2 && bi##TM > cj); \
  bool hr = (bd##T > d2) || (bd##T == d2 && bi##T > cj); \
  float nd = sh ? bd##TM : (hr ? d2 : bd##T); \
  int   ni = sh ? bi##TM : (hr ? cj : bi##T); \
  bd##T = nd; bi##T = ni; }
#define INS2_CHAIN() \
  INS2(15,14) INS2(14,13) INS2(13,12) INS2(12,11) INS2(11,10) INS2(10,9) INS2(9,8) INS2(8,7) \
  INS2(7,6) INS2(6,5) INS2(5,4) INS2(4,3) INS2(3,2) INS2(2,1) INS2(1,0) \
  { bool hr = (bd0 > d2) || (bd0 == d2 && bi0 > cj); bd0 = hr ? d2 : bd0; bi0 = hr ? cj : bi0; }
#define DECL16() \
  float bd0=3e38f,bd1=3e38f,bd2=3e38f,bd3=3e38f,bd4=3e38f,bd5=3e38f,bd6=3e38f,bd7=3e38f, \
        bd8=3e38f,bd9=3e38f,bd10=3e38f,bd11=3e38f,bd12=3e38f,bd13=3e38f,bd14=3e38f,bd15=3e38f; \
  int   bi0=0x7fffffff,bi1=0x7fffffff,bi2=0x7fffffff,bi3=0x7fffffff,bi4=0x7fffffff,bi5=0x7fffffff, \
        bi6=0x7fffffff,bi7=0x7fffffff,bi8=0x7fffffff,bi9=0x7fffffff,bi10=0x7fffffff,bi11=0x7fffffff, \
        bi12=0x7fffffff,bi13=0x7fffffff,bi14=0x7fffffff,bi15=0x7fffffff;

__global__ __launch_bounds__(256) void k_knn2(const float* __restrict__ sd, const int* __restrict__ si,
                                              const int* __restrict__ cnt, int* __restrict__ idx) {
  int m = blockIdx.x * 256 + threadIdx.x;
  int n = cnt[m]; if (n > CAP) n = CAP;
  DECL16();
  size_t base = (size_t)m * CAP;
  for (int t = 0; t < n; t++) {
    float d2 = sd[base + t];
    int cj = si[base + t];
    if ((d2 < bd15) || (d2 == bd15 && cj < bi15)) {
      INS2_CHAIN();
    }
  }
  const float RAD2 = (float)(0.1 * 0.1);
  int self = bi0;
  size_t o = (size_t)m * KNN;
  idx[o+0]  = (bd0  <= RAD2) ? bi0  : self;
  idx[o+1]  = (bd1  <= RAD2) ? bi1  : self;
  idx[o+2]  = (bd2  <= RAD2) ? bi2  : self;
  idx[o+3]  = (bd3  <= RAD2) ? bi3  : self;
  idx[o+4]  = (bd4  <= RAD2) ? bi4  : self;
  idx[o+5]  = (bd5  <= RAD2) ? bi5  : self;
  idx[o+6]  = (bd6  <= RAD2) ? bi6  : self;
  idx[o+7]  = (bd7  <= RAD2) ? bi7  : self;
  idx[o+8]  = (bd8  <= RAD2) ? bi8  : self;
  idx[o+9]  = (bd9  <= RAD2) ? bi9  : self;
  idx[o+10] = (bd10 <= RAD2) ? bi10 : self;
  idx[o+11] = (bd11 <= RAD2) ? bi11 : self;
  idx[o+12] = (bd12 <= RAD2) ? bi12 : self;
  idx[o+13] = (bd13 <= RAD2) ? bi13 : self;
  idx[o+14] = (bd14 <= RAD2) ? bi14 : self;
  idx[o+15] = (bd15 <= RAD2) ? bi15 : self;
}

// per-point G build (bf16 out)
__global__ __launch_bounds__(128) void k_gbuild(const float* __restrict__ xyz, const float* __restrict__ kpts,
                                                const int* __restrict__ idx, const float* __restrict__ F,
                                                ushort_t* __restrict__ G, int m_base) {
  int m = m_base + blockIdx.x;
  int tid = threadIdx.x;
  __shared__ int s_idx[KNN];
  __shared__ float4 s_rel[KNN];
  __shared__ float s_infl[KNN][44];
  if (tid < KNN) {
    int nk = idx[(size_t)m*KNN + tid];
    s_idx[tid] = nk;
    float ox = xyz[3*m], oy = xyz[3*m+1], oz = xyz[3*m+2];
    s_rel[tid] = make_float4(xyz[3*nk] - ox, xyz[3*nk+1] - oy, xyz[3*nk+2] - oz, 0.f);
  }
  if (tid >= 64 && tid < 64 + KNN) s_infl[tid - 64][43] = 0.f;
  __syncthreads();
  for (int t = tid; t < KNN*NKP; t += 128) {
    int k = t / NKP, p = t - k*NKP;
    float4 r = s_rel[k];
    float dx = r.x - kpts[3*p], dy = r.y - kpts[3*p+1], dz = r.z - kpts[3*p+2];
    float d = sqrtf(((dx*dx + dy*dy) + dz*dz) + 1e-12f);
    s_infl[k][p] = fmaxf(0.f, 1.0f - d / 0.1f);
  }
  __syncthreads();
  float nr[KNN];
  #pragma unroll
  for (int k = 0; k < KNN; k++) nr[k] = F[(size_t)s_idx[k]*CH_C + tid];
  size_t base = (size_t)(m - m_base) * PCSZ + tid;
  #pragma unroll
  for (int p4 = 0; p4 < 11; p4++) {
    float a0 = 0.f, a1 = 0.f, a2 = 0.f, a3 = 0.f;
    #pragma unroll
    for (int k = 0; k < KNN; k++) {
      const float4 iv = *(const float4*)&s_infl[k][p4*4];
      float f = nr[k];
      a0 += iv.x * f; a1 += iv.y * f; a2 += iv.z * f; a3 += iv.w * f;
    }
    int p = p4 * 4;
    G[base + (size_t)p*CH_C] = f2bf(a0);
    if (p + 1 < NKP) G[base + (size_t)(p+1)*CH_C] = f2bf(a1);
    if (p + 2 < NKP) G[base + (size_t)(p+2)*CH_C] = f2bf(a2);
    if (p + 3 < NKP) G[base + (size_t)(p+3)*CH_C] = f2bf(a3);
  }
}

// bf16 MFMA GEMM v4: M-tile 32, KC=64 per stage, 512 threads (8 waves = 2 row x 4 col), N=128.
// grid (M/32, ksplit). ksplit==1: store per mode (1:+addb, 3: addb+sig(gateb)*v, 5:+addb+gateb).
// ksplit>1: O pre-zeroed; atomicAdd; ky==0 folds residual(s).
__global__ __launch_bounds__(512) void k_bgemm(const ushort_t* __restrict__ A, const ushort_t* __restrict__ BT,
                                               float* __restrict__ O, const float* __restrict__ addb,
                                               const float* __restrict__ gateb, int K, int mode, int ksplit) {
  const int m0 = blockIdx.x * 32;
  const int ky = blockIdx.y;
  const int KH = K / ksplit;
  const int kbase = ky * KH;
  const int tid = threadIdx.x;
  const int wave = tid >> 6, lane = tid & 63;
  const int wrow = (wave & 1) * 16;       // 2 row groups of 16
  const int wcol = (wave >> 1) * 32;      // 4 col groups of 32
  __shared__ ushort_t As[32][72];
  __shared__ ushort_t Bs[128][72];
  f32x4 acc0 = {0.f,0.f,0.f,0.f}, acc1 = {0.f,0.f,0.f,0.f};
  // A staging: 32 rows x 64 k; uint2 (4 shorts)/lane; quarter-wave = 1 row, consecutive -> conflict-free
  const int a_row = tid >> 4, a_k = (tid & 15) * 4;
  // B staging: row-per-lane, 4 k-segments of 16; 2x uint4 per thread; 2-way max
  const int b_row = tid & 127, b_k = (tid >> 7) * 16;
  const ushort_t* Ap = A + (size_t)(m0 + a_row)*K + kbase + a_k;
  const ushort_t* Bp = BT + (size_t)b_row*K + kbase + b_k;
  uint2 a_reg = *(const uint2*)Ap;
  uint4 b_reg0 = *(const uint4*)Bp;
  uint4 b_reg1 = *(const uint4*)(Bp + 8);
  const int fr = lane & 15, fk = (lane >> 4) * 8;
  for (int kk = 0; kk < KH; kk += 64) {
    __syncthreads();
    *(uint2*)&As[a_row][a_k] = a_reg;
    *(uint4*)&Bs[b_row][b_k] = b_reg0;
    *(uint4*)&Bs[b_row][b_k + 8] = b_reg1;
    if (kk + 64 < KH) {
      a_reg = *(const uint2*)(Ap + kk + 64);
      b_reg0 = *(const uint4*)(Bp + kk + 64);
      b_reg1 = *(const uint4*)(Bp + kk + 72);
    }
    __syncthreads();
    #pragma unroll
    for (int sub = 0; sub < 2; sub++) {
      int ko = sub*32 + fk;
      bf16x8 af  = *(const bf16x8*)&As[wrow + fr][ko];
      bf16x8 bf0 = *(const bf16x8*)&Bs[wcol + fr][ko];
      bf16x8 bf1 = *(const bf16x8*)&Bs[wcol + 16 + fr][ko];
      acc0 = __builtin_amdgcn_mfma_f32_16x16x32_bf16(af, bf0, acc0, 0, 0, 0);
      acc1 = __builtin_amdgcn_mfma_f32_16x16x32_bf16(af, bf1, acc1, 0, 0, 0);
    }
  }
  const int ocol = lane & 15, orow4 = (lane >> 4) * 4;
  #pragma unroll
  for (int r = 0; r < 4; r++) {
    int row = m0 + wrow + orow4 + r;
    size_t o0 = (size_t)row * 128 + wcol + ocol;
    size_t o1 = o0 + 16;
    float v0 = acc0[r], v1 = acc1[r];
    if (ksplit == 1) {
      if (mode == 1)      { O[o0] = v0 + addb[o0]; O[o1] = v1 + addb[o1]; }
      else if (mode == 3) { O[o0] = addb[o0] + v0 / (1.f + expf(-gateb[o0]));
                            O[o1] = addb[o1] + v1 / (1.f + expf(-gateb[o1])); }
      else                { O[o0] = v0 + addb[o0] + gateb[o0]; O[o1] = v1 + addb[o1] + gateb[o1]; }
    } else {
      if (ky == 0) {
        v0 += addb[o0]; v1 += addb[o1];
        if (mode == 5) { v0 += gateb[o0]; v1 += gateb[o1]; }
      }
      atomicAdd(&O[o0], v0);
      atomicAdd(&O[o1], v1);
    }
  }
}

// ---- fused small GEMMs: K=128 in-LDS, A built on the fly ----

__device__ __forceinline__ void fill_B128(ushort_t Bs[128][136], const ushort_t* __restrict__ BT, int tid) {
  int row = tid & 127, seg = tid >> 7;
  const ushort_t* src = BT + (size_t)row*128 + seg*64;
  #pragma unroll
  for (int j = 0; j < 8; j++)
    *(uint4*)&Bs[row][seg*64 + j*8] = *(const uint4*)(src + j*8);
}

__device__ __forceinline__ void fill_A_mix(ushort_t As[32][136], const float* __restrict__ XN,
                                           const float* __restrict__ mix, int m0, int tid) {
  int row = tid >> 3, c0 = (tid & 7) * 16;
  int m = m0 + row;
  int n = m & 4095;
  #pragma unroll
  for (int j = 0; j < 4; j++) {
    int c = c0 + j*4;
    float4 xv = *(const float4*)(XN + (size_t)m*128 + c);
    float4 sv = make_float4(0.f,0.f,0.f,0.f);
    if (n != 0) sv = *(const float4*)(XN + (size_t)(m-1)*128 + c);
    float4 mv = *(const float4*)(mix + c);
    As[row][c+0] = f2bf(xv.x*mv.x + sv.x*(1.f-mv.x));
    As[row][c+1] = f2bf(xv.y*mv.y + sv.y*(1.f-mv.y));
    As[row][c+2] = f2bf(xv.z*mv.z + sv.z*(1.f-mv.z));
    As[row][c+3] = f2bf(xv.w*mv.w + sv.w*(1.f-mv.w));
  }
}

__device__ __forceinline__ void fill_A_gate(ushort_t As[32][136], const float* __restrict__ RR,
                                            const float* __restrict__ WKV, int m0, int tid) {
  int row = tid >> 3, c0 = (tid & 7) * 16;
  size_t base = (size_t)(m0 + row)*128 + c0;
  #pragma unroll
  for (int j = 0; j < 4; j++) {
    float4 rv = *(const float4*)(RR + base + j*4);
    float4 wv = *(const float4*)(WKV + base + j*4);
    As[row][c0+j*4+0] = f2bf(wv.x / (1.f + expf(-rv.x)));
    As[row][c0+j*4+1] = f2bf(wv.y / (1.f + expf(-rv.y)));
    As[row][c0+j*4+2] = f2bf(wv.z / (1.f + expf(-rv.z)));
    As[row][c0+j*4+3] = f2bf(wv.w / (1.f + expf(-rv.w)));
  }
}

__device__ __forceinline__ void fgemm_core(const ushort_t As[32][136], const ushort_t Bs[128][136],
                                           int wrow, int wcol, int lane, f32x4 acc[4]) {
  const int fr = lane & 15, fk = (lane >> 4) * 8;
  #pragma unroll
  for (int ck = 0; ck < 4; ck++) {
    int ko = ck*32 + fk;
    bf16x8 af  = *(const bf16x8*)&As[wrow + fr][ko];
    bf16x8 bf0 = *(const bf16x8*)&Bs[wcol + fr][ko];
    bf16x8 bf1 = *(const bf16x8*)&Bs[wcol + 16 + fr][ko];
    bf16x8 bf2 = *(const bf16x8*)&Bs[wcol + 32 + fr][ko];
    bf16x8 bf3 = *(const bf16x8*)&Bs[wcol + 48 + fr][ko];
    acc[0] = __builtin_amdgcn_mfma_f32_16x16x32_bf16(af, bf0, acc[0], 0, 0, 0);
    acc[1] = __builtin_amdgcn_mfma_f32_16x16x32_bf16(af, bf1, acc[1], 0, 0, 0);
    acc[2] = __builtin_amdgcn_mfma_f32_16x16x32_bf16(af, bf2, acc[2], 0, 0, 0);
    acc[3] = __builtin_amdgcn_mfma_f32_16x16x32_bf16(af, bf3, acc[3], 0, 0, 0);
  }
}

// qkv: grid (M/32, 3); out f32 [M][128]
__global__ __launch_bounds__(256) void k_qkv(const float* __restrict__ XN,
                                             const float* __restrict__ mk, const float* __restrict__ mv,
                                             const float* __restrict__ mr, const ushort_t* __restrict__ WTA,
                                             float* __restrict__ O0, float* __restrict__ O1, float* __restrict__ O2) {
  const int m0 = blockIdx.x * 32;
  const int y = blockIdx.y;
  const float* mix = (y == 0) ? mk : (y == 1) ? mv : mr;
  const ushort_t* BT = WTA + (size_t)y * 16384;
  float* O = (y == 0) ? O0 : (y == 1) ? O1 : O2;
  const int tid = threadIdx.x;
  const int wave = tid >> 6, lane = tid & 63;
  const int wrow = (wave & 1) * 16, wcol = (wave >> 1) * 64;
  __shared__ ushort_t As[32][136];
  __shared__ ushort_t Bs[128][136];
  fill_A_mix(As, XN, mix, m0, tid);
  fill_B128(Bs, BT, tid);
  __syncthreads();
  f32x4 acc[4];
  #pragma unroll
  for (int j = 0; j < 4; j++) acc[j] = (f32x4){0.f,0.f,0.f,0.f};
  fgemm_core(As, Bs, wrow, wcol, lane, acc);
  int ocol = lane & 15, orow4 = (lane >> 4) * 4;
  #pragma unroll
  for (int r = 0; r < 4; r++) {
    size_t o = (size_t)(m0 + wrow + orow4 + r) * 128 + wcol + ocol;
    O[o] = acc[0][r]; O[o+16] = acc[1][r]; O[o+32] = acc[2][r]; O[o+48] = acc[3][r];
  }
}

// att out-proj: A = wkv*sigmoid(rr); O = A@atto^T + P. grid (M/32)
__global__ __launch_bounds__(256) void k_att(const float* __restrict__ RR, const float* __restrict__ WKV,
                                             const ushort_t* __restrict__ BT, const float* __restrict__ addb,
                                             float* __restrict__ O) {
  const int m0 = blockIdx.x * 32;
  const int tid = threadIdx.x;
  const int wave = tid >> 6, lane = tid & 63;
  const int wrow = (wave & 1) * 16, wcol = (wave >> 1) * 64;
  __shared__ ushort_t As[32][136];
  __shared__ ushort_t Bs[128][136];
  fill_A_gate(As, RR, WKV, m0, tid);
  fill_B128(Bs, BT, tid);
  __syncthreads();
  f32x4 acc[4];
  #pragma unroll
  for (int j = 0; j < 4; j++) acc[j] = (f32x4){0.f,0.f,0.f,0.f};
  fgemm_core(As, Bs, wrow, wcol, lane, acc);
  int ocol = lane & 15, orow4 = (lane >> 4) * 4;
  #pragma unroll
  for (int r = 0; r < 4; r++) {
    size_t o = (size_t)(m0 + wrow + orow4 + r) * 128 + wcol + ocol;
    O[o]    = acc[0][r] + addb[o];
    O[o+16] = acc[1][r] + addb[o+16];
    O[o+32] = acc[2][r] + addb[o+32];
    O[o+48] = acc[3][r] + addb[o+48];
  }
}

// ffn: grid (M/32, 5). y<4: HID n-block y = relu^2 -> bf16 [M][512]; y==4: r-gate f32 [M][128]
__global__ __launch_bounds__(256) void k_ffn(const float* __restrict__ XN,
                                             const float* __restrict__ cmk, const float* __restrict__ cmr,
                                             const ushort_t* __restrict__ WTfk, const ushort_t* __restrict__ WTr,
                                             ushort_t* __restrict__ HID, float* __restrict__ ORR) {
  const int m0 = blockIdx.x * 32;
  const int y = blockIdx.y;
  const float* mix = (y < 4) ? cmk : cmr;
  const ushort_t* BT = (y < 4) ? (WTfk + (size_t)y * 16384) : WTr;
  const int tid = threadIdx.x;
  const int wave = tid >> 6, lane = tid & 63;
  const int wrow = (wave & 1) * 16, wcol = (wave >> 1) * 64;
  __shared__ ushort_t As[32][136];
  __shared__ ushort_t Bs[128][136];
  fill_A_mix(As, XN, mix, m0, tid);
  fill_B128(Bs, BT, tid);
  __syncthreads();
  f32x4 acc[4];
  #pragma unroll
  for (int j = 0; j < 4; j++) acc[j] = (f32x4){0.f,0.f,0.f,0.f};
  fgemm_core(As, Bs, wrow, wcol, lane, acc);
  int ocol = lane & 15, orow4 = (lane >> 4) * 4;
  #pragma unroll
  for (int r = 0; r < 4; r++) {
    int row = m0 + wrow + orow4 + r;
    if (y < 4) {
      size_t o = (size_t)row * 512 + y*128 + wcol + ocol;
      #pragma unroll
      for (int j = 0; j < 4; j++) {
        float t = fmaxf(acc[j][r], 0.f);
        HID[o + j*16] = f2bf(t*t);
      }
    } else {
      size_t o = (size_t)row * 128 + wcol + ocol;
      ORR[o] = acc[0][r]; ORR[o+16] = acc[1][r]; ORR[o+32] = acc[2][r]; ORR[o+48] = acc[3][r];
    }
  }
}

__global__ __launch_bounds__(256) void k_ln(const float* __restrict__ P, float* __restrict__ XN,
                                            const float* __restrict__ g, const float* __restrict__ bvec) {
  int w = threadIdx.x >> 6, lane = threadIdx.x & 63;
  size_t m = (size_t)blockIdx.x * 4 + w;
  const float* row = P + m * 128;
  float v0 = row[lane], v1 = row[lane + 64];
  float s = v0 + v1;
  for (int o = 32; o; o >>= 1) s += __shfl_xor(s, o);
  float mu = s * (1.f/128.f);
  float d0 = v0 - mu, d1 = v1 - mu;
  float q = d0*d0 + d1*d1;
  for (int o = 32; o; o >>= 1) q += __shfl_xor(q, o);
  float rstd = 1.f / sqrtf(q * (1.f/128.f) + 1e-5f);
  XN[m*128 + lane]      = d0 * rstd * g[lane]      + bvec[lane];
  XN[m*128 + lane + 64] = d1 * rstd * g[lane + 64] + bvec[lane + 64];
}

// ---- chunked parallel WKV scan ----
__global__ __launch_bounds__(256) void k_wkv1(const float* __restrict__ KK, const float* __restrict__ VV,
                                              float* __restrict__ sum, const float* __restrict__ td) {
  int ch = blockIdx.x, bc = threadIdx.x;
  int b = bc >> 7, c = bc & 127;
  float w = -expf(td[c]);
  float aa = 0.f, bb = 0.f, pp = -1e38f;
  size_t base = (size_t)b * NPTS * 128 + (size_t)ch * CHL * 128 + c;
  for (int t = 0; t < CHL; t++) {
    float kt = KK[base + (size_t)t*128], vt = VV[base + (size_t)t*128];
    float ww2 = pp + w;
    float q2 = fmaxf(ww2, kt);
    float e1 = expf(ww2 - q2), e2 = expf(kt - q2);
    aa = e1*aa + e2*vt; bb = e1*bb + e2; pp = q2;
  }
  sum[ch*256 + bc] = aa;
  sum[NCH*256 + ch*256 + bc] = bb;
  sum[2*NCH*256 + ch*256 + bc] = pp;
}

__global__ __launch_bounds__(256) void k_wkv2(const float* __restrict__ sum, float* __restrict__ carry,
                                              const float* __restrict__ td) {
  int bc = threadIdx.x;
  int c = bc & 127;
  float Lw = -expf(td[c]) * (float)CHL;
  float aa = 0.f, bb = 0.f, pp = -1e38f;
  for (int ch = 0; ch < NCH; ch++) {
    carry[ch*256 + bc] = aa;
    carry[NCH*256 + ch*256 + bc] = bb;
    carry[2*NCH*256 + ch*256 + bc] = pp;
    float sa = sum[ch*256 + bc];
    float sb = sum[NCH*256 + ch*256 + bc];
    float sp = sum[2*NCH*256 + ch*256 + bc];
    float p1 = pp + Lw;
    float q = fmaxf(p1, sp);
    float e1 = expf(p1 - q), e2 = expf(sp - q);
    aa = e1*aa + e2*sa; bb = e1*bb + e2*sb; pp = q;
  }
}

__global__ __launch_bounds__(256) void k_wkv3(const float* __restrict__ KK, const float* __restrict__ VV,
                                              float* __restrict__ OUT, const float* __restrict__ carry,
                                              const float* __restrict__ td, const float* __restrict__ tf) {
  int ch = blockIdx.x, bc = threadIdx.x;
  int b = bc >> 7, c = bc & 127;
  float w = -expf(td[c]);
  float tfc = tf[c];
  float aa = carry[ch*256 + bc];
  float bb = carry[NCH*256 + ch*256 + bc];
  float pp = carry[2*NCH*256 + ch*256 + bc];
  size_t base = (size_t)b * NPTS * 128 + (size_t)ch * CHL * 128 + c;
  for (int t = 0; t < CHL; t++) {
    float kt = KK[base + (size_t)t*128], vt = VV[base + (size_t)t*128];
    float ww = tfc + kt;
    float q = fmaxf(pp, ww);
    float e1 = expf(pp - q), e2 = expf(ww - q);
    OUT[base + (size_t)t*128] = (e1*aa + e2*vt) / (e1*bb + e2);
    float ww2 = pp + w;
    float q2 = fmaxf(ww2, kt);
    e1 = expf(ww2 - q2); e2 = expf(kt - q2);
    aa = e1*aa + e2*vt; bb = e1*bb + e2; pp = q2;
  }
}

__global__ __launch_bounds__(256) void k_bn1(const float* __restrict__ P3, double* __restrict__ part) {
  int bk = blockIdx.x;
  int c = threadIdx.x & 127, h = threadIdx.x >> 7;
  double s = 0.0, q = 0.0;
  for (int r = h; r < 128; r += 2) {
    double v = (double)P3[(size_t)(bk*128 + r)*128 + c];
    s += v; q += v*v;
  }
  __shared__ double ss[256], sq2[256];
  ss[threadIdx.x] = s; sq2[threadIdx.x] = q;
  __syncthreads();
  if (h == 0) {
    part[(size_t)(bk*128 + c)*2]     = s + ss[threadIdx.x + 128];
    part[(size_t)(bk*128 + c)*2 + 1] = q + sq2[threadIdx.x + 128];
  }
}

__global__ void k_bn2(const double* __restrict__ part, float* __restrict__ stats) {
  int c = threadIdx.x;
  double S = 0.0, Q = 0.0;
  for (int bk = 0; bk < 64; bk++) {
    S += part[(size_t)(bk*128 + c)*2];
    Q += part[(size_t)(bk*128 + c)*2 + 1];
  }
  double mean = S / 8192.0;
  double var = Q / 8192.0 - mean*mean;
  stats[c] = (float)mean;
  stats[128 + c] = (float)(1.0 / sqrt(var + 1e-5));
}

__global__ __launch_bounds__(128) void k_label(const float* __restrict__ P3, const float* __restrict__ stats,
                                               const float* __restrict__ bng, const float* __restrict__ bnb,
                                               const float* __restrict__ convw, const float* __restrict__ convb,
                                               float* __restrict__ label) {
  int m = blockIdx.x, c = threadIdx.x;
  __shared__ float yn[128];
  float v = P3[(size_t)m*128 + c];
  float t = (v - stats[c]) * stats[128 + c] * bng[c] + bnb[c];
  yn[c] = fmaxf(t, 0.f);
  __syncthreads();
  if (c < 16) {
    float acc = convb[c];
    #pragma unroll 8
    for (int k = 0; k < 128; k++) acc += yn[k] * convw[c*128 + k];
    int b = m >> 12, n = m & 4095;
    label[(size_t)b*65536 + (size_t)c*4096 + n] = acc;
  }
}

// ---------------- host ----------------
extern "C" void kernel_launch(void* const* d_in, const int* in_sizes, int n_in,
                              void* d_out, int out_size, void* d_ws, size_t ws_size,
                              hipStream_t stream) {
  (void)in_sizes; (void)n_in; (void)out_size;
  const float* p     = (const float*)d_in[0];
  const float* x     = (const float*)d_in[1];
  const float* kp1w  = (const float*)d_in[2];
  const float* kp2w  = (const float*)d_in[3];
  const float* ln1g  = (const float*)d_in[4];
  const float* ln1b  = (const float*)d_in[5];
  const float* td    = (const float*)d_in[6];
  const float* tf    = (const float*)d_in[7];
  const float* mixk  = (const float*)d_in[8];
  const float* mixv  = (const float*)d_in[9];
  const float* mixr  = (const float*)d_in[10];
  const float* attwk = (const float*)d_in[11];
  const float* attwv = (const float*)d_in[12];
  const float* attwr = (const float*)d_in[13];
  const float* attwo = (const float*)d_in[14];
  const float* ln2g  = (const float*)d_in[15];
  const float* ln2b  = (const float*)d_in[16];
  const float* cmixk = (const float*)d_in[17];
  const float* cmixr = (const float*)d_in[18];
  const float* ffnwk = (const float*)d_in[19];
  const float* ffnwv = (const float*)d_in[20];
  const float* ffnwr = (const float*)d_in[21];
  const float* bng   = (const float*)d_in[22];
  const float* bnb   = (const float*)d_in[23];
  const float* convw = (const float*)d_in[24];
  const float* convb = (const float*)d_in[25];

  float* W = (float*)d_ws;
  float* xyz  = W + OFF_XYZ;
  float* sq   = W + OFF_SQ;
  float* kpts = W + OFF_KPTS;
  float* bnst = W + OFF_BNST;
  double* bnp = (double*)(W + OFF_BNP);
  int* idx    = (int*)(W + OFF_IDX);
  float* F0   = W + OFF_BUF + 0ull*1048576ull;
  float* F1   = W + OFF_BUF + 1ull*1048576ull;
  float* F2   = W + OFF_BUF + 2ull*1048576ull;  // P, later P3
  float* XN   = W + OFF_BUF + 3ull*1048576ull;
  float* KKb  = W + OFF_BUF + 5ull*1048576ull;  // later P2
  float* VVb  = W + OFF_BUF + 6ull*1048576ull;
  float* RRb  = W + OFF_BUF + 7ull*1048576ull;
  float* WKVb = W + OFF_BUF + 8ull*1048576ull;
  ushort_t* Gbf = (ushort_t*)(W + OFF_G);       // bf16 G [CHK][5504]
  ushort_t* HIDu = (ushort_t*)(W + OFF_G);      // bf16 hidden [8192][512]
  float* sd   = W + OFF_G;                      // knn survivor dists [M*CAP]
  int*   si   = (int*)(W + OFF_G + 1048576ull); // knn survivor idx   [M*CAP]
  int*   scnt = (int*)(W + OFF_G + 2097152ull); // per-query survivor count
  float* wsum = W + OFF_G;
  float* wcar = W + OFF_G + 3ull*NCH*256ull;
  ushort_t* WT1 = (ushort_t*)(W + OFF_WT1);
  ushort_t* WT2 = (ushort_t*)(W + OFF_WT2);
  ushort_t* WTA = (ushort_t*)(W + OFF_WTA);     // attk, attv, attr, atto, ffnr (5 x 16384)
  ushort_t* WTfk = (ushort_t*)(W + OFF_WTFK);   // [512][128]
  ushort_t* WTfv = (ushort_t*)(W + OFF_WTFV);   // [128][512]

  // chunk size for bf16 G vs ws_size
  const size_t HIDSLOTS = 8192ull * 512ull / 2ull;
  int CHK = 512;
  const int cands[5] = {8192, 4096, 2048, 1024, 512};
  for (int ci = 0; ci < 5; ci++) {
    size_t gfl = ((size_t)cands[ci] * (size_t)PCSZ + 1) / 2;
    size_t used = OFF_G + (gfl > HIDSLOTS ? gfl : HIDSLOTS);
    size_t top = used > WS_TOP ? used : WS_TOP;
    if (top * 4ull <= ws_size) { CHK = cands[ci]; break; }
  }

  float* y_out = (float*)d_out;
  float* label_out = y_out + 1048576ull;

  hipLaunchKernelGGL(k_kpts, dim3(1), dim3(64), 0, stream, kpts);
  hipLaunchKernelGGL(k_zero, dim3(32), dim3(256), 0, stream, scnt);
  hipLaunchKernelGGL(k_zerof, dim3(8192), dim3(256), 0, stream, F1);  // zeros F1 and F2 (contiguous)
  hipLaunchKernelGGL(k_prep, dim3(32), dim3(256), 0, stream, p, xyz, sq);
  hipLaunchKernelGGL(k_tx, dim3(128, 4, 2), dim3(32, 8), 0, stream, x, F0);
  hipLaunchKernelGGL(k_wt, dim3(PCSZ/32, 4), dim3(256), 0, stream, kp1w, WT1, PCSZ, 128);
  hipLaunchKernelGGL(k_wt, dim3(PCSZ/32, 4), dim3(256), 0, stream, kp2w, WT2, PCSZ, 128);
  hipLaunchKernelGGL(k_wt5, dim3(4, 4, 5), dim3(256), 0, stream, attwk, attwv, attwr, attwo, ffnwr, WTA);
  hipLaunchKernelGGL(k_wt, dim3(4, 16), dim3(256), 0, stream, ffnwk, WTfk, 128, 512);
  hipLaunchKernelGGL(k_wt, dim3(16, 4), dim3(256), 0, stream, ffnwv, WTfv, 512, 128);
  hipLaunchKernelGGL(k_knna, dim3(MTOT/32), dim3(1024), 0, stream, xyz, sq, sd, si, scnt);
  hipLaunchKernelGGL(k_knn2, dim3(MTOT/256), dim3(256), 0, stream, sd, si, scnt, idx);

  // KPConv block 1: F1 = G(F0) @ kp1w + F0   (split-K x2 atomic, F1 pre-zeroed)
  for (int mb = 0; mb < MTOT; mb += CHK) {
    hipLaunchKernelGGL(k_gbuild, dim3(CHK), dim3(128), 0, stream, xyz, kpts, idx, F0, Gbf, mb);
    hipLaunchKernelGGL(k_bgemm, dim3(CHK/32, 2), dim3(512), 0, stream,
                       Gbf, WT1, F1 + (size_t)mb*128, F0 + (size_t)mb*128, (const float*)nullptr, PCSZ, 1, 2);
  }
  // KPConv block 2 (+ both residuals): F2 = G(F1) @ kp2w + F1 + F0 = P
  for (int mb = 0; mb < MTOT; mb += CHK) {
    hipLaunchKernelGGL(k_gbuild, dim3(CHK), dim3(128), 0, stream, xyz, kpts, idx, F1, Gbf, mb);
    hipLaunchKernelGGL(k_bgemm, dim3(CHK/32, 2), dim3(512), 0, stream,
                       Gbf, WT2, F2 + (size_t)mb*128, F1 + (size_t)mb*128, F0 + (size_t)mb*128, PCSZ, 5, 2);
  }

  // spatial mix
  hipLaunchKernelGGL(k_ln, dim3(2048), dim3(256), 0, stream, F2, XN, ln1g, ln1b);
  hipLaunchKernelGGL(k_qkv, dim3(256, 3), dim3(256), 0, stream, XN, mixk, mixv, mixr, WTA, KKb, VVb, RRb);
  hipLaunchKernelGGL(k_wkv1, dim3(NCH), dim3(256), 0, stream, KKb, VVb, wsum, td);
  hipLaunchKernelGGL(k_wkv2, dim3(1), dim3(256), 0, stream, wsum, wcar, td);
  hipLaunchKernelGGL(k_wkv3, dim3(NCH), dim3(256), 0, stream, KKb, VVb, WKVb, wcar, td, tf);
  // P2 = (wkv*sigmoid(r)) @ att_wo + P   (into KKb)
  hipLaunchKernelGGL(k_att, dim3(256), dim3(256), 0, stream, RRb, WKVb, WTA + 49152, F2, KKb);

  // channel mix
  hipLaunchKernelGGL(k_ln, dim3(2048), dim3(256), 0, stream, KKb, XN, ln2g, ln2b);
  hipLaunchKernelGGL(k_ffn, dim3(256, 5), dim3(256), 0, stream, XN, cmixk, cmixr, WTfk, WTA + 65536, HIDu, RRb);
  // P3 = P2 + sigmoid(rgate) * (HID @ ffn_wv)   (into F2) — gated epilogue, no split
  hipLaunchKernelGGL(k_bgemm, dim3(MTOT/32, 1), dim3(512), 0, stream, HIDu, WTfv, F2, KKb, RRb, 512, 3, 1);

  // outputs
  hipLaunchKernelGGL(k_bn1, dim3(64), dim3(256), 0, stream, F2, bnp);
  hipLaunchKernelGGL(k_bn2, dim3(1), dim3(128), 0, stream, bnp, bnst);
  hipLaunchKernelGGL(k_ty, dim3(128, 4, 2), dim3(32, 8), 0, stream, F2, y_out);
  hipLaunchKernelGGL(k_label, dim3(8192), dim3(128), 0, stream, F2, bnst, bng, bnb, convw, convb, label_out);
}

// Round 11
// 470.982 us; speedup vs baseline: 1.1144x; 1.1144x over previous
//
#include <hip/hip_runtime.h>
#include <math.h>

#define BATCH 2
#define NPTS 4096
#define CH_C 128
#define MTOT 8192
#define KNN 16
#define NKP 43
#define PCSZ (NKP*CH_C)   // 5504
#define NCH 128           // wkv chunks
#define CHL (NPTS/NCH)    // 32 steps per chunk
#define CAP 128           // survivor list cap per query

typedef unsigned short ushort_t;
typedef __attribute__((ext_vector_type(8))) short bf16x8;
typedef __attribute__((ext_vector_type(4))) float f32x4;

// ---------------- ws layout (float offsets) ----------------
static const size_t OFF_XYZ  = 0;                       // 24576 floats
static const size_t OFF_SQ   = 24576;                   // 8192
static const size_t OFF_KPTS = 32768;                   // 129 -> pad 256
static const size_t OFF_BNST = 33024;                   // 256 (mu,rstd)
static const size_t OFF_BNP  = 33280;                   // doubles: 16384 d
static const size_t OFF_IDX  = 66048;                   // ints: 131072
static const size_t OFF_BUF  = 197120;                  // 9 x 1048576 float buffers
static const size_t OFF_G    = OFF_BUF + 9ull*1048576ull; // 9634304
// G region time-shared: knn sd/si/cnt -> KPConv G(bf16) -> wkv sum/carry -> HIDu(bf16)
static const size_t OFF_WT1  = OFF_G + 22544384ull;     // bf16 5504*128 = 352256 float slots
static const size_t OFF_WT2  = OFF_WT1 + 352256ull;
static const size_t OFF_WTA  = OFF_WT2 + 352256ull;     // 5 x 128x128 bf16 = 40960 slots
static const size_t OFF_WTFK = OFF_WTA + 40960ull;      // 512x128 bf16 = 32768 slots
static const size_t OFF_WTFV = OFF_WTFK + 32768ull;     // 128x512 bf16 = 32768 slots
static const size_t WS_TOP   = OFF_WTFV + 32768ull;

__device__ inline ushort_t f2bf(float f) {
  unsigned int u = __builtin_bit_cast(unsigned int, f);
  u = u + 0x7fffu + ((u >> 16) & 1u);
  return (ushort_t)(u >> 16);
}

// ---------------- kernels ----------------

// fused init: blocks [0,8192) zero F1+F2; [8192,8224) prep+scnt-zero; 8224 kpts
__global__ __launch_bounds__(256) void k_init(const float* __restrict__ p, float* __restrict__ xyz,
                                              float* __restrict__ sq, int* __restrict__ cnt,
                                              float* __restrict__ kpts, float* __restrict__ Fzero) {
  int bx = blockIdx.x, tid = threadIdx.x;
  if (bx < 8192) {
    Fzero[(size_t)bx * 256 + tid] = 0.f;
    return;
  }
  if (bx < 8224) {
    int m = (bx - 8192) * 256 + tid;
    int b = m >> 12, n = m & 4095;
    float px = p[(size_t)b*12288 + n];
    float py = p[(size_t)b*12288 + 4096 + n];
    float pz = p[(size_t)b*12288 + 8192 + n];
    xyz[3*m] = px; xyz[3*m+1] = py; xyz[3*m+2] = pz;
    sq[m] = (px*px + py*py) + pz*pz;
    cnt[m] = 0;
    return;
  }
  // kpts
  int i = tid;
  if (i >= NKP) return;
  double px = 0.0, py = 0.0, pz = 0.0;
  if (i > 0) {
    int mcount = (i < 15) ? 14 : 28;
    int ii = (i < 15) ? (i - 1) : (i - 15);
    double scale = (i < 15) ? (0.1 * 0.5) : 0.1;
    double id = (double)ii + 0.5;
    double phi = acos(1.0 - 2.0 * id / (double)mcount);
    double theta = M_PI * (1.0 + sqrt(5.0)) * id;
    px = cos(theta) * sin(phi) * scale;
    py = sin(theta) * sin(phi) * scale;
    pz = cos(phi) * scale;
  }
  kpts[3*i] = (float)px; kpts[3*i+1] = (float)py; kpts[3*i+2] = (float)pz;
}

// x [B,C,N] -> F0 [M][C]
__global__ __launch_bounds__(256) void k_tx(const float* __restrict__ x, float* __restrict__ F0) {
  __shared__ float t[32][33];
  int b = blockIdx.z;
  int n0 = blockIdx.x * 32, c0 = blockIdx.y * 32;
  int tx = threadIdx.x, ty = threadIdx.y;
  #pragma unroll
  for (int i = 0; i < 4; i++)
    t[ty + i*8][tx] = x[(size_t)b*524288 + (size_t)(c0 + ty + i*8)*4096 + n0 + tx];
  __syncthreads();
  #pragma unroll
  for (int i = 0; i < 4; i++)
    F0[(size_t)(b*4096 + n0 + ty + i*8)*128 + c0 + tx] = t[tx][ty + i*8];
}

// P3 [M][C] -> y [B,C,N]
__global__ __launch_bounds__(256) void k_ty(const float* __restrict__ P3, float* __restrict__ y) {
  __shared__ float t[32][33];
  int b = blockIdx.z;
  int n0 = blockIdx.x * 32, c0 = blockIdx.y * 32;
  int tx = threadIdx.x, ty = threadIdx.y;
  #pragma unroll
  for (int i = 0; i < 4; i++)
    t[ty + i*8][tx] = P3[(size_t)(b*4096 + n0 + ty + i*8)*128 + c0 + tx];
  __syncthreads();
  #pragma unroll
  for (int i = 0; i < 4; i++)
    y[(size_t)b*524288 + (size_t)(c0 + ty + i*8)*4096 + n0 + tx] = t[tx][ty + i*8];
}

// all weight transposes in one kernel. 32x32 tiles, range-switched.
__global__ __launch_bounds__(256) void k_wtall(const float* kp1w, const float* kp2w,
                                               const float* attwk, const float* attwv, const float* attwr,
                                               const float* attwo, const float* ffnwr,
                                               const float* ffnwk, const float* ffnwv,
                                               ushort_t* WT1, ushort_t* WT2, ushort_t* WTA,
                                               ushort_t* WTfk, ushort_t* WTfv) {
  int bx = blockIdx.x;
  const float* src; ushort_t* dst; int K, N, k0, n0;
  if (bx < 688) {            // kp1w [5504][128]
    src = kp1w; dst = WT1; K = PCSZ; N = 128; k0 = (bx >> 2) * 32; n0 = (bx & 3) * 32;
  } else if (bx < 1376) {    // kp2w
    int t = bx - 688;
    src = kp2w; dst = WT2; K = PCSZ; N = 128; k0 = (t >> 2) * 32; n0 = (t & 3) * 32;
  } else if (bx < 1456) {    // five 128x128
    int t = bx - 1376; int w = t >> 4; int tt = t & 15;
    src = (w==0)?attwk:(w==1)?attwv:(w==2)?attwr:(w==3)?attwo:ffnwr;
    dst = WTA + (size_t)w * 16384;
    K = 128; N = 128; k0 = (tt >> 2) * 32; n0 = (tt & 3) * 32;
  } else if (bx < 1520) {    // ffnwk [128][512]
    int t = bx - 1456;
    src = ffnwk; dst = WTfk; K = 128; N = 512; k0 = (t & 3) * 32; n0 = (t >> 2) * 32;
  } else {                   // ffnwv [512][128]
    int t = bx - 1520;
    src = ffnwv; dst = WTfv; K = 512; N = 128; k0 = (t >> 2) * 32; n0 = (t & 3) * 32;
  }
  __shared__ float tl[32][33];
  int tx = threadIdx.x & 31, ty = threadIdx.x >> 5;
  #pragma unroll
  for (int i = 0; i < 4; i++)
    tl[ty + i*8][tx] = src[(size_t)(k0 + ty + i*8)*N + n0 + tx];
  __syncthreads();
  #pragma unroll
  for (int i = 0; i < 4; i++)
    dst[(size_t)(n0 + ty + i*8)*K + k0 + tx] = f2bf(tl[tx][ty + i*8]);
}

// phase A: radius compaction. 32 queries/block x 32 segments of 128 cands.
__global__ __launch_bounds__(1024) void k_knna(const float* __restrict__ xyz, const float* __restrict__ sq,
                                               float* __restrict__ sd, int* __restrict__ si,
                                               int* __restrict__ cnt) {
  __shared__ float4 s_c[NPTS];
  int tid = threadIdx.x;
  int m0 = blockIdx.x * 32;
  int b = m0 >> 12;
  int jbase = b << 12;
  for (int j = tid; j < NPTS; j += 1024) {
    int jj = jbase + j;
    s_c[j] = make_float4(xyz[3*jj], xyz[3*jj+1], xyz[3*jj+2], sq[jj]);
  }
  __syncthreads();
  int q = tid & 31, s = tid >> 5;
  int m = m0 + q;
  int lq = m - jbase;
  float4 me = s_c[lq];
  float ox = me.x, oy = me.y, oz = me.z, osq = me.w;
  const float RAD2 = (float)(0.1 * 0.1);
  int cbase = s * 128;
  for (int jj = 0; jj < 128; jj++) {
    float4 cp = s_c[cbase + jj];
    float dot = (ox*cp.x + oy*cp.y) + oz*cp.z;
    float d2 = (osq + cp.w) - 2.0f*dot;
    if (d2 <= RAD2) {
      int pos = atomicAdd(&cnt[m], 1);
      if (pos < CAP) {
        sd[(size_t)m*CAP + pos] = d2;
        si[(size_t)m*CAP + pos] = jbase + cbase + jj;
      }
    }
  }
}

// phase B: deterministic top-16 via (d2, idx)-lexicographic insert chain
#define INS2(T,TM) { bool sh = (bd##TM > d2) || (bd##TM == d2 && bi##TM > cj); \
  bool hr = (bd##T > d2) || (bd##T == d2 && bi##T > cj); \
  float nd = sh ? bd##TM : (hr ? d2 : bd##T); \
  int   ni = sh ? bi##TM : (hr ? cj : bi##T); \
  bd##T = nd; bi##T = ni; }
#define INS2_CHAIN() \
  INS2(15,14) INS2(14,13) INS2(13,12) INS2(12,11) INS2(11,10) INS2(10,9) INS2(9,8) INS2(8,7) \
  INS2(7,6) INS2(6,5) INS2(5,4) INS2(4,3) INS2(3,2) INS2(2,1) INS2(1,0) \
  { bool hr = (bd0 > d2) || (bd0 == d2 && bi0 > cj); bd0 = hr ? d2 : bd0; bi0 = hr ? cj : bi0; }
#define DECL16() \
  float bd0=3e38f,bd1=3e38f,bd2=3e38f,bd3=3e38f,bd4=3e38f,bd5=3e38f,bd6=3e38f,bd7=3e38f, \
        bd8=3e38f,bd9=3e38f,bd10=3e38f,bd11=3e38f,bd12=3e38f,bd13=3e38f,bd14=3e38f,bd15=3e38f; \
  int   bi0=0x7fffffff,bi1=0x7fffffff,bi2=0x7fffffff,bi3=0x7fffffff,bi4=0x7fffffff,bi5=0x7fffffff, \
        bi6=0x7fffffff,bi7=0x7fffffff,bi8=0x7fffffff,bi9=0x7fffffff,bi10=0x7fffffff,bi11=0x7fffffff, \
        bi12=0x7fffffff,bi13=0x7fffffff,bi14=0x7fffffff,bi15=0x7fffffff;

__global__ __launch_bounds__(256) void k_knn2(const float* __restrict__ sd, const int* __restrict__ si,
                                              const int* __restrict__ cnt, int* __restrict__ idx) {
  int m = blockIdx.x * 256 + threadIdx.x;
  int n = cnt[m]; if (n > CAP) n = CAP;
  DECL16();
  size_t base = (size_t)m * CAP;
  for (int t = 0; t < n; t++) {
    float d2 = sd[base + t];
    int cj = si[base + t];
    if ((d2 < bd15) || (d2 == bd15 && cj < bi15)) {
      INS2_CHAIN();
    }
  }
  const float RAD2 = (float)(0.1 * 0.1);
  int self = bi0;
  size_t o = (size_t)m * KNN;
  idx[o+0]  = (bd0  <= RAD2) ? bi0  : self;
  idx[o+1]  = (bd1  <= RAD2) ? bi1  : self;
  idx[o+2]  = (bd2  <= RAD2) ? bi2  : self;
  idx[o+3]  = (bd3  <= RAD2) ? bi3  : self;
  idx[o+4]  = (bd4  <= RAD2) ? bi4  : self;
  idx[o+5]  = (bd5  <= RAD2) ? bi5  : self;
  idx[o+6]  = (bd6  <= RAD2) ? bi6  : self;
  idx[o+7]  = (bd7  <= RAD2) ? bi7  : self;
  idx[o+8]  = (bd8  <= RAD2) ? bi8  : self;
  idx[o+9]  = (bd9  <= RAD2) ? bi9  : self;
  idx[o+10] = (bd10 <= RAD2) ? bi10 : self;
  idx[o+11] = (bd11 <= RAD2) ? bi11 : self;
  idx[o+12] = (bd12 <= RAD2) ? bi12 : self;
  idx[o+13] = (bd13 <= RAD2) ? bi13 : self;
  idx[o+14] = (bd14 <= RAD2) ? bi14 : self;
  idx[o+15] = (bd15 <= RAD2) ? bi15 : self;
}

// per-point G build (bf16 out)
__global__ __launch_bounds__(128) void k_gbuild(const float* __restrict__ xyz, const float* __restrict__ kpts,
                                                const int* __restrict__ idx, const float* __restrict__ F,
                                                ushort_t* __restrict__ G, int m_base) {
  int m = m_base + blockIdx.x;
  int tid = threadIdx.x;
  __shared__ int s_idx[KNN];
  __shared__ float4 s_rel[KNN];
  __shared__ float s_infl[KNN][44];
  if (tid < KNN) {
    int nk = idx[(size_t)m*KNN + tid];
    s_idx[tid] = nk;
    float ox = xyz[3*m], oy = xyz[3*m+1], oz = xyz[3*m+2];
    s_rel[tid] = make_float4(xyz[3*nk] - ox, xyz[3*nk+1] - oy, xyz[3*nk+2] - oz, 0.f);
  }
  if (tid >= 64 && tid < 64 + KNN) s_infl[tid - 64][43] = 0.f;
  __syncthreads();
  for (int t = tid; t < KNN*NKP; t += 128) {
    int k = t / NKP, p = t - k*NKP;
    float4 r = s_rel[k];
    float dx = r.x - kpts[3*p], dy = r.y - kpts[3*p+1], dz = r.z - kpts[3*p+2];
    float d = sqrtf(((dx*dx + dy*dy) + dz*dz) + 1e-12f);
    s_infl[k][p] = fmaxf(0.f, 1.0f - d / 0.1f);
  }
  __syncthreads();
  float nr[KNN];
  #pragma unroll
  for (int k = 0; k < KNN; k++) nr[k] = F[(size_t)s_idx[k]*CH_C + tid];
  size_t base = (size_t)(m - m_base) * PCSZ + tid;
  #pragma unroll
  for (int p4 = 0; p4 < 11; p4++) {
    float a0 = 0.f, a1 = 0.f, a2 = 0.f, a3 = 0.f;
    #pragma unroll
    for (int k = 0; k < KNN; k++) {
      const float4 iv = *(const float4*)&s_infl[k][p4*4];
      float f = nr[k];
      a0 += iv.x * f; a1 += iv.y * f; a2 += iv.z * f; a3 += iv.w * f;
    }
    int p = p4 * 4;
    G[base + (size_t)p*CH_C] = f2bf(a0);
    if (p + 1 < NKP) G[base + (size_t)(p+1)*CH_C] = f2bf(a1);
    if (p + 2 < NKP) G[base + (size_t)(p+2)*CH_C] = f2bf(a2);
    if (p + 3 < NKP) G[base + (size_t)(p+3)*CH_C] = f2bf(a3);
  }
}

// bf16 MFMA GEMM (R8-proven config): M-tile 32, KC=32, 512 threads (8 waves = 2 row x 4 col), N=128.
// grid (M/32, ksplit). ksplit==1: store per mode (1:+addb, 3: addb+sig(gateb)*v, 5:+addb+gateb).
// ksplit==2: O pre-zeroed; atomicAdd; ky==0 folds residual(s).
__global__ __launch_bounds__(512) void k_bgemm(const ushort_t* __restrict__ A, const ushort_t* __restrict__ BT,
                                               float* __restrict__ O, const float* __restrict__ addb,
                                               const float* __restrict__ gateb, int K, int mode, int ksplit) {
  const int m0 = blockIdx.x * 32;
  const int ky = blockIdx.y;
  const int KH = K / ksplit;
  const int kbase = ky * KH;
  const int tid = threadIdx.x;
  const int wave = tid >> 6, lane = tid & 63;
  const int wrow = (wave & 1) * 16;       // 2 row groups of 16
  const int wcol = (wave >> 1) * 32;      // 4 col groups of 32
  __shared__ ushort_t As[32][40];
  __shared__ ushort_t Bs[128][40];
  f32x4 acc0 = {0.f,0.f,0.f,0.f}, acc1 = {0.f,0.f,0.f,0.f};
  // staging indices: A 32x32 (1 word/lane), B 128x32 (uint4/lane)
  const int a_row = tid >> 4, a_k = (tid & 15) * 2;
  const int b_row = tid >> 2, b_k = (tid & 3) * 8;
  const ushort_t* Ap = A + (size_t)(m0 + a_row)*K + kbase + a_k;
  const ushort_t* Bp = BT + (size_t)b_row*K + kbase + b_k;
  unsigned int a_reg = *(const unsigned int*)Ap;
  uint4 b_reg = *(const uint4*)Bp;
  const int fr = lane & 15, fk = (lane >> 4) * 8;
  for (int kk = 0; kk < KH; kk += 32) {
    __syncthreads();
    *(unsigned int*)&As[a_row][a_k] = a_reg;
    *(uint4*)&Bs[b_row][b_k] = b_reg;
    if (kk + 32 < KH) {
      a_reg = *(const unsigned int*)(Ap + kk + 32);
      b_reg = *(const uint4*)(Bp + kk + 32);
    }
    __syncthreads();
    bf16x8 af  = *(const bf16x8*)&As[wrow + fr][fk];
    bf16x8 bf0 = *(const bf16x8*)&Bs[wcol + fr][fk];
    bf16x8 bf1 = *(const bf16x8*)&Bs[wcol + 16 + fr][fk];
    acc0 = __builtin_amdgcn_mfma_f32_16x16x32_bf16(af, bf0, acc0, 0, 0, 0);
    acc1 = __builtin_amdgcn_mfma_f32_16x16x32_bf16(af, bf1, acc1, 0, 0, 0);
  }
  const int ocol = lane & 15, orow4 = (lane >> 4) * 4;
  #pragma unroll
  for (int r = 0; r < 4; r++) {
    int row = m0 + wrow + orow4 + r;
    size_t o0 = (size_t)row * 128 + wcol + ocol;
    size_t o1 = o0 + 16;
    float v0 = acc0[r], v1 = acc1[r];
    if (ksplit == 1) {
      if (mode == 1)      { O[o0] = v0 + addb[o0]; O[o1] = v1 + addb[o1]; }
      else if (mode == 3) { O[o0] = addb[o0] + v0 / (1.f + expf(-gateb[o0]));
                            O[o1] = addb[o1] + v1 / (1.f + expf(-gateb[o1])); }
      else                { O[o0] = v0 + addb[o0] + gateb[o0]; O[o1] = v1 + addb[o1] + gateb[o1]; }
    } else {
      if (ky == 0) {
        v0 += addb[o0]; v1 += addb[o1];
        if (mode == 5) { v0 += gateb[o0]; v1 += gateb[o1]; }
      }
      atomicAdd(&O[o0], v0);
      atomicAdd(&O[o1], v1);
    }
  }
}

// ---- fused small GEMMs: K=128 in-LDS, A built on the fly ----

__device__ __forceinline__ void fill_B128(ushort_t Bs[128][136], const ushort_t* __restrict__ BT, int tid) {
  int row = tid & 127, seg = tid >> 7;
  const ushort_t* src = BT + (size_t)row*128 + seg*64;
  #pragma unroll
  for (int j = 0; j < 8; j++)
    *(uint4*)&Bs[row][seg*64 + j*8] = *(const uint4*)(src + j*8);
}

__device__ __forceinline__ void fill_A_mix(ushort_t As[32][136], const float* __restrict__ XN,
                                           const float* __restrict__ mix, int m0, int tid) {
  int row = tid >> 3, c0 = (tid & 7) * 16;
  int m = m0 + row;
  int n = m & 4095;
  #pragma unroll
  for (int j = 0; j < 4; j++) {
    int c = c0 + j*4;
    float4 xv = *(const float4*)(XN + (size_t)m*128 + c);
    float4 sv = make_float4(0.f,0.f,0.f,0.f);
    if (n != 0) sv = *(const float4*)(XN + (size_t)(m-1)*128 + c);
    float4 mv = *(const float4*)(mix + c);
    As[row][c+0] = f2bf(xv.x*mv.x + sv.x*(1.f-mv.x));
    As[row][c+1] = f2bf(xv.y*mv.y + sv.y*(1.f-mv.y));
    As[row][c+2] = f2bf(xv.z*mv.z + sv.z*(1.f-mv.z));
    As[row][c+3] = f2bf(xv.w*mv.w + sv.w*(1.f-mv.w));
  }
}

__device__ __forceinline__ void fill_A_gate(ushort_t As[32][136], const float* __restrict__ RR,
                                            const float* __restrict__ WKV, int m0, int tid) {
  int row = tid >> 3, c0 = (tid & 7) * 16;
  size_t base = (size_t)(m0 + row)*128 + c0;
  #pragma unroll
  for (int j = 0; j < 4; j++) {
    float4 rv = *(const float4*)(RR + base + j*4);
    float4 wv = *(const float4*)(WKV + base + j*4);
    As[row][c0+j*4+0] = f2bf(wv.x / (1.f + expf(-rv.x)));
    As[row][c0+j*4+1] = f2bf(wv.y / (1.f + expf(-rv.y)));
    As[row][c0+j*4+2] = f2bf(wv.z / (1.f + expf(-rv.z)));
    As[row][c0+j*4+3] = f2bf(wv.w / (1.f + expf(-rv.w)));
  }
}

__device__ __forceinline__ void fgemm_core(const ushort_t As[32][136], const ushort_t Bs[128][136],
                                           int wrow, int wcol, int lane, f32x4 acc[4]) {
  const int fr = lane & 15, fk = (lane >> 4) * 8;
  #pragma unroll
  for (int ck = 0; ck < 4; ck++) {
    int ko = ck*32 + fk;
    bf16x8 af  = *(const bf16x8*)&As[wrow + fr][ko];
    bf16x8 bf0 = *(const bf16x8*)&Bs[wcol + fr][ko];
    bf16x8 bf1 = *(const bf16x8*)&Bs[wcol + 16 + fr][ko];
    bf16x8 bf2 = *(const bf16x8*)&Bs[wcol + 32 + fr][ko];
    bf16x8 bf3 = *(const bf16x8*)&Bs[wcol + 48 + fr][ko];
    acc[0] = __builtin_amdgcn_mfma_f32_16x16x32_bf16(af, bf0, acc[0], 0, 0, 0);
    acc[1] = __builtin_amdgcn_mfma_f32_16x16x32_bf16(af, bf1, acc[1], 0, 0, 0);
    acc[2] = __builtin_amdgcn_mfma_f32_16x16x32_bf16(af, bf2, acc[2], 0, 0, 0);
    acc[3] = __builtin_amdgcn_mfma_f32_16x16x32_bf16(af, bf3, acc[3], 0, 0, 0);
  }
}

// qkv: grid (M/32, 3); out f32 [M][128]
__global__ __launch_bounds__(256) void k_qkv(const float* __restrict__ XN,
                                             const float* __restrict__ mk, const float* __restrict__ mv,
                                             const float* __restrict__ mr, const ushort_t* __restrict__ WTA,
                                             float* __restrict__ O0, float* __restrict__ O1, float* __restrict__ O2) {
  const int m0 = blockIdx.x * 32;
  const int y = blockIdx.y;
  const float* mix = (y == 0) ? mk : (y == 1) ? mv : mr;
  const ushort_t* BT = WTA + (size_t)y * 16384;
  float* O = (y == 0) ? O0 : (y == 1) ? O1 : O2;
  const int tid = threadIdx.x;
  const int wave = tid >> 6, lane = tid & 63;
  const int wrow = (wave & 1) * 16, wcol = (wave >> 1) * 64;
  __shared__ ushort_t As[32][136];
  __shared__ ushort_t Bs[128][136];
  fill_A_mix(As, XN, mix, m0, tid);
  fill_B128(Bs, BT, tid);
  __syncthreads();
  f32x4 acc[4];
  #pragma unroll
  for (int j = 0; j < 4; j++) acc[j] = (f32x4){0.f,0.f,0.f,0.f};
  fgemm_core(As, Bs, wrow, wcol, lane, acc);
  int ocol = lane & 15, orow4 = (lane >> 4) * 4;
  #pragma unroll
  for (int r = 0; r < 4; r++) {
    size_t o = (size_t)(m0 + wrow + orow4 + r) * 128 + wcol + ocol;
    O[o] = acc[0][r]; O[o+16] = acc[1][r]; O[o+32] = acc[2][r]; O[o+48] = acc[3][r];
  }
}

// att out-proj: A = wkv*sigmoid(rr); O = A@atto^T + P. grid (M/32)
__global__ __launch_bounds__(256) void k_att(const float* __restrict__ RR, const float* __restrict__ WKV,
                                             const ushort_t* __restrict__ BT, const float* __restrict__ addb,
                                             float* __restrict__ O) {
  const int m0 = blockIdx.x * 32;
  const int tid = threadIdx.x;
  const int wave = tid >> 6, lane = tid & 63;
  const int wrow = (wave & 1) * 16, wcol = (wave >> 1) * 64;
  __shared__ ushort_t As[32][136];
  __shared__ ushort_t Bs[128][136];
  fill_A_gate(As, RR, WKV, m0, tid);
  fill_B128(Bs, BT, tid);
  __syncthreads();
  f32x4 acc[4];
  #pragma unroll
  for (int j = 0; j < 4; j++) acc[j] = (f32x4){0.f,0.f,0.f,0.f};
  fgemm_core(As, Bs, wrow, wcol, lane, acc);
  int ocol = lane & 15, orow4 = (lane >> 4) * 4;
  #pragma unroll
  for (int r = 0; r < 4; r++) {
    size_t o = (size_t)(m0 + wrow + orow4 + r) * 128 + wcol + ocol;
    O[o]    = acc[0][r] + addb[o];
    O[o+16] = acc[1][r] + addb[o+16];
    O[o+32] = acc[2][r] + addb[o+32];
    O[o+48] = acc[3][r] + addb[o+48];
  }
}

// ffn: grid (M/32, 5). y<4: HID n-block y = relu^2 -> bf16 [M][512]; y==4: r-gate f32 [M][128]
__global__ __launch_bounds__(256) void k_ffn(const float* __restrict__ XN,
                                             const float* __restrict__ cmk, const float* __restrict__ cmr,
                                             const ushort_t* __restrict__ WTfk, const ushort_t* __restrict__ WTr,
                                             ushort_t* __restrict__ HID, float* __restrict__ ORR) {
  const int m0 = blockIdx.x * 32;
  const int y = blockIdx.y;
  const float* mix = (y < 4) ? cmk : cmr;
  const ushort_t* BT = (y < 4) ? (WTfk + (size_t)y * 16384) : WTr;
  const int tid = threadIdx.x;
  const int wave = tid >> 6, lane = tid & 63;
  const int wrow = (wave & 1) * 16, wcol = (wave >> 1) * 64;
  __shared__ ushort_t As[32][136];
  __shared__ ushort_t Bs[128][136];
  fill_A_mix(As, XN, mix, m0, tid);
  fill_B128(Bs, BT, tid);
  __syncthreads();
  f32x4 acc[4];
  #pragma unroll
  for (int j = 0; j < 4; j++) acc[j] = (f32x4){0.f,0.f,0.f,0.f};
  fgemm_core(As, Bs, wrow, wcol, lane, acc);
  int ocol = lane & 15, orow4 = (lane >> 4) * 4;
  #pragma unroll
  for (int r = 0; r < 4; r++) {
    int row = m0 + wrow + orow4 + r;
    if (y < 4) {
      size_t o = (size_t)row * 512 + y*128 + wcol + ocol;
      #pragma unroll
      for (int j = 0; j < 4; j++) {
        float t = fmaxf(acc[j][r], 0.f);
        HID[o + j*16] = f2bf(t*t);
      }
    } else {
      size_t o = (size_t)row * 128 + wcol + ocol;
      ORR[o] = acc[0][r]; ORR[o+16] = acc[1][r]; ORR[o+32] = acc[2][r]; ORR[o+48] = acc[3][r];
    }
  }
}

__global__ __launch_bounds__(256) void k_ln(const float* __restrict__ P, float* __restrict__ XN,
                                            const float* __restrict__ g, const float* __restrict__ bvec) {
  int w = threadIdx.x >> 6, lane = threadIdx.x & 63;
  size_t m = (size_t)blockIdx.x * 4 + w;
  const float* row = P + m * 128;
  float v0 = row[lane], v1 = row[lane + 64];
  float s = v0 + v1;
  for (int o = 32; o; o >>= 1) s += __shfl_xor(s, o);
  float mu = s * (1.f/128.f);
  float d0 = v0 - mu, d1 = v1 - mu;
  float q = d0*d0 + d1*d1;
  for (int o = 32; o; o >>= 1) q += __shfl_xor(q, o);
  float rstd = 1.f / sqrtf(q * (1.f/128.f) + 1e-5f);
  XN[m*128 + lane]      = d0 * rstd * g[lane]      + bvec[lane];
  XN[m*128 + lane + 64] = d1 * rstd * g[lane + 64] + bvec[lane + 64];
}

// ---- chunked parallel WKV scan ----
__global__ __launch_bounds__(256) void k_wkv1(const float* __restrict__ KK, const float* __restrict__ VV,
                                              float* __restrict__ sum, const float* __restrict__ td) {
  int ch = blockIdx.x, bc = threadIdx.x;
  int b = bc >> 7, c = bc & 127;
  float w = -expf(td[c]);
  float aa = 0.f, bb = 0.f, pp = -1e38f;
  size_t base = (size_t)b * NPTS * 128 + (size_t)ch * CHL * 128 + c;
  for (int t = 0; t < CHL; t++) {
    float kt = KK[base + (size_t)t*128], vt = VV[base + (size_t)t*128];
    float ww2 = pp + w;
    float q2 = fmaxf(ww2, kt);
    float e1 = expf(ww2 - q2), e2 = expf(kt - q2);
    aa = e1*aa + e2*vt; bb = e1*bb + e2; pp = q2;
  }
  sum[ch*256 + bc] = aa;
  sum[NCH*256 + ch*256 + bc] = bb;
  sum[2*NCH*256 + ch*256 + bc] = pp;
}

__global__ __launch_bounds__(256) void k_wkv2(const float* __restrict__ sum, float* __restrict__ carry,
                                              const float* __restrict__ td) {
  int bc = threadIdx.x;
  int c = bc & 127;
  float Lw = -expf(td[c]) * (float)CHL;
  float aa = 0.f, bb = 0.f, pp = -1e38f;
  for (int ch = 0; ch < NCH; ch++) {
    carry[ch*256 + bc] = aa;
    carry[NCH*256 + ch*256 + bc] = bb;
    carry[2*NCH*256 + ch*256 + bc] = pp;
    float sa = sum[ch*256 + bc];
    float sb = sum[NCH*256 + ch*256 + bc];
    float sp = sum[2*NCH*256 + ch*256 + bc];
    float p1 = pp + Lw;
    float q = fmaxf(p1, sp);
    float e1 = expf(p1 - q), e2 = expf(sp - q);
    aa = e1*aa + e2*sa; bb = e1*bb + e2*sb; pp = q;
  }
}

__global__ __launch_bounds__(256) void k_wkv3(const float* __restrict__ KK, const float* __restrict__ VV,
                                              float* __restrict__ OUT, const float* __restrict__ carry,
                                              const float* __restrict__ td, const float* __restrict__ tf) {
  int ch = blockIdx.x, bc = threadIdx.x;
  int b = bc >> 7, c = bc & 127;
  float w = -expf(td[c]);
  float tfc = tf[c];
  float aa = carry[ch*256 + bc];
  float bb = carry[NCH*256 + ch*256 + bc];
  float pp = carry[2*NCH*256 + ch*256 + bc];
  size_t base = (size_t)b * NPTS * 128 + (size_t)ch * CHL * 128 + c;
  for (int t = 0; t < CHL; t++) {
    float kt = KK[base + (size_t)t*128], vt = VV[base + (size_t)t*128];
    float ww = tfc + kt;
    float q = fmaxf(pp, ww);
    float e1 = expf(pp - q), e2 = expf(ww - q);
    OUT[base + (size_t)t*128] = (e1*aa + e2*vt) / (e1*bb + e2);
    float ww2 = pp + w;
    float q2 = fmaxf(ww2, kt);
    e1 = expf(ww2 - q2); e2 = expf(kt - q2);
    aa = e1*aa + e2*vt; bb = e1*bb + e2; pp = q2;
  }
}

__global__ __launch_bounds__(256) void k_bn1(const float* __restrict__ P3, double* __restrict__ part) {
  int bk = blockIdx.x;
  int c = threadIdx.x & 127, h = threadIdx.x >> 7;
  double s = 0.0, q = 0.0;
  for (int r = h; r < 128; r += 2) {
    double v = (double)P3[(size_t)(bk*128 + r)*128 + c];
    s += v; q += v*v;
  }
  __shared__ double ss[256], sq2[256];
  ss[threadIdx.x] = s; sq2[threadIdx.x] = q;
  __syncthreads();
  if (h == 0) {
    part[(size_t)(bk*128 + c)*2]     = s + ss[threadIdx.x + 128];
    part[(size_t)(bk*128 + c)*2 + 1] = q + sq2[threadIdx.x + 128];
  }
}

__global__ void k_bn2(const double* __restrict__ part, float* __restrict__ stats) {
  int c = threadIdx.x;
  double S = 0.0, Q = 0.0;
  for (int bk = 0; bk < 64; bk++) {
    S += part[(size_t)(bk*128 + c)*2];
    Q += part[(size_t)(bk*128 + c)*2 + 1];
  }
  double mean = S / 8192.0;
  double var = Q / 8192.0 - mean*mean;
  stats[c] = (float)mean;
  stats[128 + c] = (float)(1.0 / sqrt(var + 1e-5));
}

__global__ __launch_bounds__(128) void k_label(const float* __restrict__ P3, const float* __restrict__ stats,
                                               const float* __restrict__ bng, const float* __restrict__ bnb,
                                               const float* __restrict__ convw, const float* __restrict__ convb,
                                               float* __restrict__ label) {
  int m = blockIdx.x, c = threadIdx.x;
  __shared__ float yn[128];
  float v = P3[(size_t)m*128 + c];
  float t = (v - stats[c]) * stats[128 + c] * bng[c] + bnb[c];
  yn[c] = fmaxf(t, 0.f);
  __syncthreads();
  if (c < 16) {
    float acc = convb[c];
    #pragma unroll 8
    for (int k = 0; k < 128; k++) acc += yn[k] * convw[c*128 + k];
    int b = m >> 12, n = m & 4095;
    label[(size_t)b*65536 + (size_t)c*4096 + n] = acc;
  }
}

// ---------------- host ----------------
extern "C" void kernel_launch(void* const* d_in, const int* in_sizes, int n_in,
                              void* d_out, int out_size, void* d_ws, size_t ws_size,
                              hipStream_t stream) {
  (void)in_sizes; (void)n_in; (void)out_size;
  const float* p     = (const float*)d_in[0];
  const float* x     = (const float*)d_in[1];
  const float* kp1w  = (const float*)d_in[2];
  const float* kp2w  = (const float*)d_in[3];
  const float* ln1g  = (const float*)d_in[4];
  const float* ln1b  = (const float*)d_in[5];
  const float* td    = (const float*)d_in[6];
  const float* tf    = (const float*)d_in[7];
  const float* mixk  = (const float*)d_in[8];
  const float* mixv  = (const float*)d_in[9];
  const float* mixr  = (const float*)d_in[10];
  const float* attwk = (const float*)d_in[11];
  const float* attwv = (const float*)d_in[12];
  const float* attwr = (const float*)d_in[13];
  const float* attwo = (const float*)d_in[14];
  const float* ln2g  = (const float*)d_in[15];
  const float* ln2b  = (const float*)d_in[16];
  const float* cmixk = (const float*)d_in[17];
  const float* cmixr = (const float*)d_in[18];
  const float* ffnwk = (const float*)d_in[19];
  const float* ffnwv = (const float*)d_in[20];
  const float* ffnwr = (const float*)d_in[21];
  const float* bng   = (const float*)d_in[22];
  const float* bnb   = (const float*)d_in[23];
  const float* convw = (const float*)d_in[24];
  const float* convb = (const float*)d_in[25];

  float* W = (float*)d_ws;
  float* xyz  = W + OFF_XYZ;
  float* sq   = W + OFF_SQ;
  float* kpts = W + OFF_KPTS;
  float* bnst = W + OFF_BNST;
  double* bnp = (double*)(W + OFF_BNP);
  int* idx    = (int*)(W + OFF_IDX);
  float* F0   = W + OFF_BUF + 0ull*1048576ull;
  float* F1   = W + OFF_BUF + 1ull*1048576ull;
  float* F2   = W + OFF_BUF + 2ull*1048576ull;  // P, later P3
  float* XN   = W + OFF_BUF + 3ull*1048576ull;
  float* KKb  = W + OFF_BUF + 5ull*1048576ull;  // later P2
  float* VVb  = W + OFF_BUF + 6ull*1048576ull;
  float* RRb  = W + OFF_BUF + 7ull*1048576ull;
  float* WKVb = W + OFF_BUF + 8ull*1048576ull;
  ushort_t* Gbf = (ushort_t*)(W + OFF_G);       // bf16 G [CHK][5504]
  ushort_t* HIDu = (ushort_t*)(W + OFF_G);      // bf16 hidden [8192][512]
  float* sd   = W + OFF_G;                      // knn survivor dists [M*CAP]
  int*   si   = (int*)(W + OFF_G + 1048576ull); // knn survivor idx   [M*CAP]
  int*   scnt = (int*)(W + OFF_G + 2097152ull); // per-query survivor count
  float* wsum = W + OFF_G;
  float* wcar = W + OFF_G + 3ull*NCH*256ull;
  ushort_t* WT1 = (ushort_t*)(W + OFF_WT1);
  ushort_t* WT2 = (ushort_t*)(W + OFF_WT2);
  ushort_t* WTA = (ushort_t*)(W + OFF_WTA);     // attk, attv, attr, atto, ffnr (5 x 16384)
  ushort_t* WTfk = (ushort_t*)(W + OFF_WTFK);   // [512][128]
  ushort_t* WTfv = (ushort_t*)(W + OFF_WTFV);   // [128][512]

  // chunk size for bf16 G vs ws_size
  const size_t HIDSLOTS = 8192ull * 512ull / 2ull;
  int CHK = 512;
  const int cands[5] = {8192, 4096, 2048, 1024, 512};
  for (int ci = 0; ci < 5; ci++) {
    size_t gfl = ((size_t)cands[ci] * (size_t)PCSZ + 1) / 2;
    size_t used = OFF_G + (gfl > HIDSLOTS ? gfl : HIDSLOTS);
    size_t top = used > WS_TOP ? used : WS_TOP;
    if (top * 4ull <= ws_size) { CHK = cands[ci]; break; }
  }

  float* y_out = (float*)d_out;
  float* label_out = y_out + 1048576ull;

  // fused init: zero F1+F2, prep xyz/sq, zero scnt, kpts
  hipLaunchKernelGGL(k_init, dim3(8225), dim3(256), 0, stream, p, xyz, sq, scnt, kpts, F1);
  hipLaunchKernelGGL(k_tx, dim3(128, 4, 2), dim3(32, 8), 0, stream, x, F0);
  hipLaunchKernelGGL(k_wtall, dim3(1584), dim3(256), 0, stream,
                     kp1w, kp2w, attwk, attwv, attwr, attwo, ffnwr, ffnwk, ffnwv,
                     WT1, WT2, WTA, WTfk, WTfv);
  hipLaunchKernelGGL(k_knna, dim3(MTOT/32), dim3(1024), 0, stream, xyz, sq, sd, si, scnt);
  hipLaunchKernelGGL(k_knn2, dim3(MTOT/256), dim3(256), 0, stream, sd, si, scnt, idx);

  // KPConv block 1: F1 = G(F0) @ kp1w + F0   (split-K x2 atomic, F1 pre-zeroed)
  for (int mb = 0; mb < MTOT; mb += CHK) {
    hipLaunchKernelGGL(k_gbuild, dim3(CHK), dim3(128), 0, stream, xyz, kpts, idx, F0, Gbf, mb);
    hipLaunchKernelGGL(k_bgemm, dim3(CHK/32, 2), dim3(512), 0, stream,
                       Gbf, WT1, F1 + (size_t)mb*128, F0 + (size_t)mb*128, (const float*)nullptr, PCSZ, 1, 2);
  }
  // KPConv block 2 (+ both residuals): F2 = G(F1) @ kp2w + F1 + F0 = P
  for (int mb = 0; mb < MTOT; mb += CHK) {
    hipLaunchKernelGGL(k_gbuild, dim3(CHK), dim3(128), 0, stream, xyz, kpts, idx, F1, Gbf, mb);
    hipLaunchKernelGGL(k_bgemm, dim3(CHK/32, 2), dim3(512), 0, stream,
                       Gbf, WT2, F2 + (size_t)mb*128, F1 + (size_t)mb*128, F0 + (size_t)mb*128, PCSZ, 5, 2);
  }

  // spatial mix
  hipLaunchKernelGGL(k_ln, dim3(2048), dim3(256), 0, stream, F2, XN, ln1g, ln1b);
  hipLaunchKernelGGL(k_qkv, dim3(256, 3), dim3(256), 0, stream, XN, mixk, mixv, mixr, WTA, KKb, VVb, RRb);
  hipLaunchKernelGGL(k_wkv1, dim3(NCH), dim3(256), 0, stream, KKb, VVb, wsum, td);
  hipLaunchKernelGGL(k_wkv2, dim3(1), dim3(256), 0, stream, wsum, wcar, td);
  hipLaunchKernelGGL(k_wkv3, dim3(NCH), dim3(256), 0, stream, KKb, VVb, WKVb, wcar, td, tf);
  // P2 = (wkv*sigmoid(r)) @ att_wo + P   (into KKb)
  hipLaunchKernelGGL(k_att, dim3(256), dim3(256), 0, stream, RRb, WKVb, WTA + 49152, F2, KKb);

  // channel mix
  hipLaunchKernelGGL(k_ln, dim3(2048), dim3(256), 0, stream, KKb, XN, ln2g, ln2b);
  hipLaunchKernelGGL(k_ffn, dim3(256, 5), dim3(256), 0, stream, XN, cmixk, cmixr, WTfk, WTA + 65536, HIDu, RRb);
  // P3 = P2 + sigmoid(rgate) * (HID @ ffn_wv)   (into F2) — gated epilogue, no split
  hipLaunchKernelGGL(k_bgemm, dim3(MTOT/32, 1), dim3(512), 0, stream, HIDu, WTfv, F2, KKb, RRb, 512, 3, 1);

  // outputs
  hipLaunchKernelGGL(k_bn1, dim3(64), dim3(256), 0, stream, F2, bnp);
  hipLaunchKernelGGL(k_bn2, dim3(1), dim3(128), 0, stream, bnp, bnst);
  hipLaunchKernelGGL(k_ty, dim3(128, 4, 2), dim3(32, 8), 0, stream, F2, y_out);
  hipLaunchKernelGGL(k_label, dim3(8192), dim3(128), 0, stream, F2, bnst, bng, bnb, convw, convb, label_out);
}